// Round 8
// baseline (1182.718 us; speedup 1.0000x reference)
//
#include <hip/hip_runtime.h>

// numpy-fp32 semantics: explicit fmaf only, no implicit contraction.
#pragma clang fp contract(off)

typedef unsigned char u8;
typedef unsigned int u32;

#define TSTEPS 4

// W LDS row addressing: pitch 68 + 16-float pad every 8 rows.
// Breaks the (8-row-stride scalar write) 4-way bank conflict down to 2-way
// (free), keeps 16B alignment for b128 compute reads.
__device__ __forceinline__ constexpr int wrow(int k) {
  return k * 68 + (k >> 3) * 16;
}

struct ConvArgs {
  const void* X1;          // fp32 (XM 0/1) or u8 spikes (XM 2)
  const u8* X2;            // XM 1: u8 spikes added in fp32 (fc1: x+attn_out)
  const float* W[4];       // per-slab weights
  const float* bn[4];      // per-slab (4,CoutTot) bn params
  const float* bias[4];    // per-slab bias or null
  u8* out[4];              // OM 0: per-slab spike outputs
  const float* Xres;       // OM 1: x
  const u8* AOres;         // OM 1: attn_out spikes
  float* Fout;             // OM 1: final fp32 out
  int oAdd[4];             // per-slab extra o offset (fc1: 0,64,128,192)
  int Bsz, Cin, CoutTot, N, OB;
};

// Fused 1x1-conv + BN + LIF. Bit-exact ascending-k fmaf chain per output
// (t outer, k-tiles ascending, kk ascending). G weight-slabs share one X
// tile; J = n-columns per thread (4 or 8; J=8 owns cols tx*4 and 64+tx*4).
// XM: 0 = fp32 X, 1 = fp32 X + u8 X2 (staged add), 2 = u8 spikes bit-packed
// in LDS (1 b128 X-read per TILE instead of 32).
// OM: 0 = u8 spike out per slab; 1 = fused final out = (x + ao) + spike.
template <int G, int J, int XM, int OM>
__global__ __launch_bounds__(256, 1) void conv_bn_lif(ConvArgs a)
{
  const int tid = threadIdx.x;
  const int tx = tid & 15, ty = tid >> 4;
  const int nBase = blockIdx.x * (J * 16);
  const int by = blockIdx.y, b = blockIdx.z;
  const int KT = a.Cin >> 5, TT = TSTEPS * KT;
  constexpr int XP  = J * 16 + 4;                 // fp32 X pitch
  constexpr int XSZ = (XM == 2) ? 64 : 32 * XP;   // floats per X buffer
  constexpr int NW  = J / 2;                      // float4 writes per thread

  __shared__ float XsF[2][XSZ];
  __shared__ float WsF[G][2][2224];

  // BN constants, correctly-rounded fp32 (double emu exact for add/sqrt/div)
  float sc[G][4], mn[G][4], bt[G][4], bi[G][4];
  #pragma unroll
  for (int g = 0; g < G; ++g) {
    #pragma unroll
    for (int i = 0; i < 4; ++i) {
      int o = by * a.OB + a.oAdd[g] + ty * 4 + i;
      float gg = a.bn[g][0 * a.CoutTot + o];
      float be = a.bn[g][1 * a.CoutTot + o];
      float m  = a.bn[g][2 * a.CoutTot + o];
      float vv = a.bn[g][3 * a.CoutTot + o];
      float d_f = (float)((double)vv + (double)1e-5f);
      float s_f = (float)sqrt((double)d_f);
      sc[g][i] = (float)((double)gg / (double)s_f);
      mn[g][i] = m; bt[g][i] = be;
      bi[g][i] = a.bias[g] ? a.bias[g][o] : 0.0f;
    }
  }

  float acc[G][4][J], mem[G][4][J];
  #pragma unroll
  for (int g = 0; g < G; ++g)
    #pragma unroll
    for (int i = 0; i < 4; ++i)
      #pragma unroll
      for (int j = 0; j < J; ++j) { acc[g][i][j] = 0.0f; mem[g][i][j] = 0.0f; }

  // staging coords
  const int xRow = tid >> 3;          // fp32 X: 0..31
  const int xCs  = (tid & 7) * 4;
  const int bKb  = tid >> 6;          // bits X: k-byte 0..3
  const int bN   = tid & 63;          //         n 0..63
  const int wO   = tid >> 2;          // W: o col 0..63
  const int wK8  = (tid & 3) * 8;     //    k row group
  const int wBase = wK8 * 68 + (tid & 3) * 16 + wO;

  float4 px[NW]; u32 pa[NW]; u32 pb8[8];
  float4 pw[G][2];

  auto issue = [&](int i) {
    const int tI = i / KT, k0 = (i % KT) << 5;
    if constexpr (XM == 2) {
      const u8* xp = (const u8*)a.X1 +
          (size_t)(tI * a.Bsz + b) * a.Cin * a.N +
          (size_t)(k0 + bKb * 8) * a.N + nBase + bN;
      #pragma unroll
      for (int j = 0; j < 8; ++j) pb8[j] = xp[(size_t)j * a.N];
    } else {
      const size_t xb0 = (size_t)(tI * a.Bsz + b) * a.Cin * a.N +
                         (size_t)(k0 + xRow) * a.N + nBase + xCs;
      #pragma unroll
      for (int jj = 0; jj < NW; ++jj) {
        px[jj] = *(const float4*)((const float*)a.X1 + xb0 + 32 * jj);
        if constexpr (XM == 1) pa[jj] = *(const u32*)(a.X2 + xb0 + 32 * jj);
      }
    }
    #pragma unroll
    for (int g = 0; g < G; ++g) {
      const float* wr = a.W[g] +
          (size_t)(by * a.OB + a.oAdd[g] + wO) * a.Cin + k0 + wK8;
      pw[g][0] = *(const float4*)wr;
      pw[g][1] = *(const float4*)(wr + 4);
    }
  };

  auto commit = [&](int buf) {
    if constexpr (XM == 2) {
      u32 v = 0;
      #pragma unroll
      for (int j = 0; j < 8; ++j) v |= (pb8[j] & 1u) << j;
      ((u8*)XsF[buf])[bN * 4 + bKb] = (u8)v;
    } else {
      float* xd = &XsF[buf][xRow * XP + xCs];
      #pragma unroll
      for (int jj = 0; jj < NW; ++jj) {
        float4 v = px[jj];
        if constexpr (XM == 1) {
          u32 av = pa[jj];
          v.x = v.x + (float)(av & 0xffu);
          v.y = v.y + (float)((av >> 8) & 0xffu);
          v.z = v.z + (float)((av >> 16) & 0xffu);
          v.w = v.w + (float)((av >> 24) & 0xffu);
        }
        *(float4*)(xd + 32 * jj) = v;
      }
    }
    #pragma unroll
    for (int g = 0; g < G; ++g) {
      float* wd = WsF[g][buf];
      #pragma unroll
      for (int i = 0; i < 4; ++i) {
        wd[wBase + (i + 0) * 68] = (&pw[g][0].x)[i];
        wd[wBase + (i + 4) * 68] = (&pw[g][1].x)[i];
      }
    }
  };

  issue(0);
  commit(0);
  __syncthreads();

  for (int tt = 0; tt < TT; ++tt) {
    const int buf = tt & 1;
    if (tt + 1 < TT) issue(tt + 1);   // keep next tile's loads in flight

    uint4 xw;
    if constexpr (XM == 2)
      xw = *(const uint4*)((const u32*)XsF[buf] + tx * 4);

    #pragma unroll
    for (int kk = 0; kk < 32; ++kk) {  // ascending k, fmaf chain (bit-exact)
      float xa[J];
      if constexpr (XM == 2) {
        xa[0] = (float)((xw.x >> kk) & 1u);
        xa[1] = (float)((xw.y >> kk) & 1u);
        xa[2] = (float)((xw.z >> kk) & 1u);
        xa[3] = (float)((xw.w >> kk) & 1u);
      } else {
        float4 v0 = *(const float4*)&XsF[buf][kk * XP + tx * 4];
        xa[0] = v0.x; xa[1] = v0.y; xa[2] = v0.z; xa[3] = v0.w;
        if constexpr (J == 8) {
          float4 v1 = *(const float4*)&XsF[buf][kk * XP + tx * 4 + 64];
          xa[4] = v1.x; xa[5] = v1.y; xa[6] = v1.z; xa[7] = v1.w;
        }
      }
      #pragma unroll
      for (int g = 0; g < G; ++g) {
        float4 wv = *(const float4*)&WsF[g][buf][wrow(kk) + ty * 4];
        float wa[4] = {wv.x, wv.y, wv.z, wv.w};
        #pragma unroll
        for (int i = 0; i < 4; ++i)
          #pragma unroll
          for (int j = 0; j < J; ++j)
            acc[g][i][j] = fmaf(wa[i], xa[j], acc[g][i][j]);
      }
    }

    if ((tt % KT) == KT - 1) {
      // epilogue for timestep t: bias + BN + LIF (reference op order)
      const int t = tt / KT;
      #pragma unroll
      for (int g = 0; g < G; ++g) {
        #pragma unroll
        for (int i = 0; i < 4; ++i) {
          const int og = by * a.OB + a.oAdd[g] + ty * 4 + i;
          #pragma unroll
          for (int s = 0; s < J / 4; ++s) {
            const size_t rb = ((size_t)(t * a.Bsz + b) * a.CoutTot + og) * a.N
                            + nBase + tx * 4 + 64 * s;
            if constexpr (OM == 0) {
              u32 pack = 0;
              #pragma unroll
              for (int j = 0; j < 4; ++j) {
                const int jj = s * 4 + j;
                float y = acc[g][i][jj] + bi[g][i];
                float t1 = y - mn[g][i];
                float t2 = t1 * sc[g][i];
                y = t2 + bt[g][i];
                float m2 = mem[g][i][jj];
                float dd = y - m2;
                m2 = m2 + dd * 0.5f;
                bool sp = (m2 - 0.5f) > 0.0f;
                mem[g][i][jj] = sp ? 0.0f : m2;
                if (sp) pack |= (1u << (8 * j));
                acc[g][i][jj] = 0.0f;
              }
              *(u32*)&a.out[g][rb] = pack;
            } else {
              float4 xr = *(const float4*)&a.Xres[rb];
              u32 av = *(const u32*)&a.AOres[rb];
              float xa4[4] = {xr.x, xr.y, xr.z, xr.w};
              float o4[4];
              #pragma unroll
              for (int j = 0; j < 4; ++j) {
                const int jj = s * 4 + j;
                float y = acc[g][i][jj] + bi[g][i];
                float t1 = y - mn[g][i];
                float t2 = t1 * sc[g][i];
                y = t2 + bt[g][i];
                float m2 = mem[g][i][jj];
                float dd = y - m2;
                m2 = m2 + dd * 0.5f;
                bool sp = (m2 - 0.5f) > 0.0f;
                mem[g][i][jj] = sp ? 0.0f : m2;
                float sv = sp ? 1.0f : 0.0f;
                float xn = xa4[j] + (float)((av >> (8 * j)) & 0xffu);
                o4[j] = xn + sv;
                acc[g][i][jj] = 0.0f;
              }
              *(float4*)&a.Fout[rb] = make_float4(o4[0], o4[1], o4[2], o4[3]);
            }
          }
        }
      }
    }

    __syncthreads();
    if (tt + 1 < TT) commit((tt + 1) & 1);
    __syncthreads();
  }
}

// Attention + attn-LIF, q @ (k^T v): integer-exact (verified R6/R7).
__global__ __launch_bounds__(256) void attn_lif(
    const u8* __restrict__ Qs, const u8* __restrict__ Ks,
    const u8* __restrict__ Vs, u8* __restrict__ Rs,
    int Bsz, int C, int N)
{
  const int tid = threadIdx.x;
  const int h = blockIdx.x & 15;
  const int b = blockIdx.x >> 4;

  __shared__ u8 qs[16][528];
  __shared__ u8 ks[16][528];
  __shared__ u8 vs[16][528];
  __shared__ int Gs[16][17];

  const int eG = tid >> 4, dG = tid & 15;
  const int dR = tid >> 4, nR0 = tid & 15;

  float mem[32];
  #pragma unroll
  for (int i = 0; i < 32; ++i) mem[i] = 0.0f;

  for (int t = 0; t < TSTEPS; ++t) {
    __syncthreads();
    const size_t base = ((size_t)(t * Bsz + b) * C + h * 16) * N;
    for (int i = 0; i < 32; ++i) {
      int flat = tid + 256 * i;
      int d = flat >> 9, n = flat & 511;
      size_t g = base + (size_t)d * N + n;
      qs[d][n] = Qs[g];
      ks[d][n] = Ks[g];
      vs[d][n] = Vs[g];
    }
    __syncthreads();

    int gi = 0;
    for (int n = 0; n < 512; ++n)
      gi += (int)ks[eG][n] * (int)vs[dG][n];
    Gs[eG][dG] = gi;
    __syncthreads();

    int Greg[16];
    #pragma unroll
    for (int e = 0; e < 16; ++e) Greg[e] = Gs[e][dR];

    const size_t obase = ((size_t)(t * Bsz + b) * C + h * 16 + dR) * N;
    for (int j = 0; j < 32; ++j) {
      int n = nR0 + 16 * j;
      int ri = 0;
      #pragma unroll
      for (int e = 0; e < 16; ++e)
        ri += qs[e][n] ? Greg[e] : 0;
      float r = (float)ri * 0.0625f;
      float m2 = mem[j];
      float d = r - m2;
      m2 = m2 + d * 0.5f;
      float s = (m2 - 0.5f) > 0.0f ? 1.0f : 0.0f;
      mem[j] = (s > 0.0f) ? 0.0f : m2;
      Rs[obase + n] = (s > 0.0f) ? (u8)1 : (u8)0;
    }
  }
}

extern "C" void kernel_launch(void* const* d_in, const int* in_sizes, int n_in,
                              void* d_out, int out_size, void* d_ws, size_t ws_size,
                              hipStream_t stream)
{
  const float* x     = (const float*)d_in[0];
  const float* q_w   = (const float*)d_in[1];
  const float* q_bn  = (const float*)d_in[2];
  const float* k_w   = (const float*)d_in[3];
  const float* k_bn  = (const float*)d_in[4];
  const float* v_w   = (const float*)d_in[5];
  const float* v_bn  = (const float*)d_in[6];
  const float* p_w   = (const float*)d_in[7];
  const float* p_bn  = (const float*)d_in[8];
  const float* f1_w  = (const float*)d_in[9];
  const float* f1_b  = (const float*)d_in[10];
  const float* f1_bn = (const float*)d_in[11];
  const float* f2_w  = (const float*)d_in[12];
  const float* f2_b  = (const float*)d_in[13];
  const float* f2_bn = (const float*)d_in[14];

  const int T = 4, B = 16, C = 256, N = 512, Hm = 1024;
  const size_t SZ = (size_t)T * B * C * N;

  // Workspace (u8 spikes), peak 5*SZ = 41.9 MB; h overlays dead q/k/v/r.
  char* ws = (char*)d_ws;
  u8* q_s  = (u8*)(ws + 0 * SZ);
  u8* k_s  = (u8*)(ws + 1 * SZ);
  u8* v_s  = (u8*)(ws + 2 * SZ);
  u8* r_s  = (u8*)(ws + 3 * SZ);
  u8* ao_s = (u8*)(ws + 4 * SZ);
  u8* h_s  = (u8*)(ws + 0 * SZ);

  dim3 blk(256);

  { // q,k,v merged: G=3 slabs share X; J=8 (64o x 128n tiles)
    ConvArgs a = {};
    a.X1 = x;
    a.W[0] = q_w; a.W[1] = k_w; a.W[2] = v_w;
    a.bn[0] = q_bn; a.bn[1] = k_bn; a.bn[2] = v_bn;
    a.out[0] = q_s; a.out[1] = k_s; a.out[2] = v_s;
    a.Bsz = B; a.Cin = C; a.CoutTot = C; a.N = N; a.OB = 64;
    conv_bn_lif<3, 8, 0, 0><<<dim3(N / 128, C / 64, B), blk, 0, stream>>>(a);
  }

  attn_lif<<<dim3(B * 16), blk, 0, stream>>>(q_s, k_s, v_s, r_s, B, C, N);

  { // proj: spike X bit-packed
    ConvArgs a = {};
    a.X1 = r_s;
    a.W[0] = p_w; a.bn[0] = p_bn; a.out[0] = ao_s;
    a.Bsz = B; a.Cin = C; a.CoutTot = C; a.N = N; a.OB = 64;
    conv_bn_lif<1, 4, 2, 0><<<dim3(N / 64, C / 64, B), blk, 0, stream>>>(a);
  }

  { // fc1: 4 o-slabs of the same weight share X = x + ao
    ConvArgs a = {};
    a.X1 = x; a.X2 = ao_s;
    for (int g = 0; g < 4; ++g) {
      a.W[g] = f1_w; a.bn[g] = f1_bn; a.bias[g] = f1_b; a.out[g] = h_s;
      a.oAdd[g] = g * 64;
    }
    a.Bsz = B; a.Cin = C; a.CoutTot = Hm; a.N = N; a.OB = 256;
    conv_bn_lif<4, 8, 1, 0><<<dim3(N / 128, Hm / 256, B), blk, 0, stream>>>(a);
  }

  { // fc2: spike X bit-packed, fused final out = (x + ao) + spike
    ConvArgs a = {};
    a.X1 = h_s;
    a.W[0] = f2_w; a.bn[0] = f2_bn; a.bias[0] = f2_b;
    a.Xres = x; a.AOres = ao_s; a.Fout = (float*)d_out;
    a.Bsz = B; a.Cin = Hm; a.CoutTot = C; a.N = N; a.OB = 64;
    conv_bn_lif<1, 4, 2, 1><<<dim3(N / 64, C / 64, B), blk, 0, stream>>>(a);
  }
}